// Round 1
// baseline (650.471 us; speedup 1.0000x reference)
//
#include <hip/hip_runtime.h>
#include <math.h>

#define HH 256
#define HW 65536
#define CIN 256
#define DLOI 128
#define NLINES 10000
#define LPB 5000

// ---------------------------------------------------------------------------
// transpose w_fc1 [128,256] -> wt [256,128] so fc1 LDS staging is coalesced
// and conflict-free.
// ---------------------------------------------------------------------------
__global__ void transpose_w_kernel(const float* __restrict__ w, float* __restrict__ wt) {
    int idx = blockIdx.x * 256 + threadIdx.x;   // 0..32767
    int c = idx >> 7;
    int o = idx & 127;
    wt[idx] = w[o * CIN + c];
}

// ---------------------------------------------------------------------------
// fc1: x[b, pix, o] = sum_c feature[b, c, pix] * w[o, c] + bias[o]
// Tile: 128 pixels x 128 outputs, K chunks of 32. fp32 vector GEMM.
// ---------------------------------------------------------------------------
__global__ __launch_bounds__(256) void fc1_kernel(
    const float* __restrict__ feat,   // [B, CIN, HW]
    const float* __restrict__ wt,     // [CIN, DLOI] (transposed)
    const float* __restrict__ bias,   // [DLOI]
    float* __restrict__ x)            // [B, HW, DLOI]
{
    __shared__ float Ft[32][128];
    __shared__ float Wt[32][128];
    const int t = threadIdx.x;
    const int blk = blockIdx.x;            // 0..1023
    const int b = blk >> 9;                // 512 blocks per batch
    const int pix0 = (blk & 511) << 7;
    const float* fbase = feat + (size_t)b * ((size_t)CIN * HW) + pix0;

    float acc[4][16];
#pragma unroll
    for (int i = 0; i < 4; i++)
#pragma unroll
        for (int j = 0; j < 16; j++) acc[i][j] = 0.f;

    const int pi0 = (t & 31) << 2;   // 4 consecutive pixels
    const int og  = (t >> 5) << 4;   // 16 consecutive outputs

    for (int k0 = 0; k0 < CIN; k0 += 32) {
        __syncthreads();
#pragma unroll
        for (int r = 0; r < 16; r++) {
            int idx = r * 256 + t;
            int c = idx >> 7;
            int q = idx & 127;
            Ft[c][q] = fbase[(size_t)(k0 + c) * HW + q];
            Wt[c][q] = wt[(k0 + c) * DLOI + q];
        }
        __syncthreads();
#pragma unroll
        for (int kk = 0; kk < 32; kk++) {
            float fv[4], wv[16];
#pragma unroll
            for (int i = 0; i < 4; i++) fv[i] = Ft[kk][pi0 + i];
#pragma unroll
            for (int j = 0; j < 16; j++) wv[j] = Wt[kk][og + j];
#pragma unroll
            for (int i = 0; i < 4; i++)
#pragma unroll
                for (int j = 0; j < 16; j++) acc[i][j] += fv[i] * wv[j];
        }
    }

    float bo[16];
#pragma unroll
    for (int j = 0; j < 16; j++) bo[j] = bias[og + j];
    for (int i = 0; i < 4; i++) {
        int pix = pi0 + i;
        float* dst = x + (size_t)(b * HW + pix0 + pix) * DLOI + og;
#pragma unroll
        for (int j = 0; j < 16; j++) dst[j] = acc[i][j] + bo[j];
    }
}

// ---------------------------------------------------------------------------
// Per-line fused kernel: bilinear sample 32 pts -> maxpool4 -> bottleneck
// (bn+relu, 1x1, bn+relu, conv3, bn+relu, 1x1, +residual) -> relu -> fc2
// -> softmax. One 256-thread block per line.
// ---------------------------------------------------------------------------
__global__ __launch_bounds__(256) void line_kernel(
    const float* __restrict__ x,      // [B, HW, DLOI] channel-last
    const float* __restrict__ lines,  // [B, L, 2, 2]
    const float* __restrict__ bn1,    // [4,128]
    const float* __restrict__ c1w,    // [64,128]
    const float* __restrict__ c1b,    // [64]
    const float* __restrict__ bn2,    // [4,64]
    const float* __restrict__ c2w,    // [64,64,3]
    const float* __restrict__ c2b,    // [64]
    const float* __restrict__ bn3,    // [4,64]
    const float* __restrict__ c3w,    // [128,64]
    const float* __restrict__ c3b,    // [128]
    const float* __restrict__ wfc2,   // [4,1024]
    const float* __restrict__ bfc2,   // [4]
    float* __restrict__ out)          // [NLINES,4]
{
    __shared__ union {
        struct {
            int   gb[4][32];
            float gw[4][32];
            float tmpmax[8][2][128];
        } ph1;
        float wbuf[3120];   // padded weight staging (stride 65 / 33)
    } u;
    __shared__ float xp[128][8];
    __shared__ float a1y[128][8];   // a1 during bottleneck, reused as y
    __shared__ float h1s[64][8];
    __shared__ float ap[64][10];    // a2 with zero padding at [0] and [9]
    __shared__ float h2s[64][8];
    __shared__ float a3s[64][8];
    __shared__ float red[16];

    const int t = threadIdx.x;
    const int n = blockIdx.x;
    const int b = (n >= LPB) ? 1 : 0;

    // ---- phase 0: per-point geometry (32 sample points) ----
    if (t < 32) {
        float l0x = lines[n * 4 + 0], l0y = lines[n * 4 + 1];
        float l1x = lines[n * 4 + 2], l1y = lines[n * 4 + 3];
        float lam = (float)t / 31.0f;
        float oml = 1.0f - lam;
        float px = l0x * lam + l1x * oml - 0.5f;
        float py = l0y * lam + l1y * oml - 0.5f;
        float px0 = fminf(fmaxf(floorf(px), 0.f), 255.f);
        float py0 = fminf(fmaxf(floorf(py), 0.f), 255.f);
        float px1 = fminf(px0 + 1.f, 255.f);
        float py1 = fminf(py0 + 1.f, 255.f);
        int i0 = (int)px0, j0 = (int)py0, i1 = (int)px1, j1 = (int)py1;
        int rb = b << 16;
        u.ph1.gb[0][t] = (rb + i0 * HH + j0) * DLOI;
        u.ph1.gb[1][t] = (rb + i1 * HH + j0) * DLOI;
        u.ph1.gb[2][t] = (rb + i0 * HH + j1) * DLOI;
        u.ph1.gb[3][t] = (rb + i1 * HH + j1) * DLOI;
        u.ph1.gw[0][t] = (px1 - px) * (py1 - py);
        u.ph1.gw[1][t] = (px - px0) * (py1 - py);
        u.ph1.gw[2][t] = (px1 - px) * (py - py0);
        u.ph1.gw[3][t] = (px - px0) * (py - py0);
    }
    __syncthreads();

    // ---- phase 1: bilinear gather + partial maxpool ----
    {
        const int ch = t & 127;
        const int sub = t >> 7;
        for (int g = 0; g < 8; g++) {
            int p0 = g * 4 + sub * 2;
            float v0 = x[u.ph1.gb[0][p0] + ch] * u.ph1.gw[0][p0]
                     + x[u.ph1.gb[1][p0] + ch] * u.ph1.gw[1][p0]
                     + x[u.ph1.gb[2][p0] + ch] * u.ph1.gw[2][p0]
                     + x[u.ph1.gb[3][p0] + ch] * u.ph1.gw[3][p0];
            int p1 = p0 + 1;
            float v1 = x[u.ph1.gb[0][p1] + ch] * u.ph1.gw[0][p1]
                     + x[u.ph1.gb[1][p1] + ch] * u.ph1.gw[1][p1]
                     + x[u.ph1.gb[2][p1] + ch] * u.ph1.gw[2][p1]
                     + x[u.ph1.gb[3][p1] + ch] * u.ph1.gw[3][p1];
            u.ph1.tmpmax[g][sub][ch] = fmaxf(v0, v1);
        }
    }
    __syncthreads();

    // ---- phase 2: finish maxpool -> xp[c][p] ----
    for (int r = 0; r < 4; r++) {
        int idx = t + 256 * r;
        int c = idx >> 3, g = idx & 7;
        xp[c][g] = fmaxf(u.ph1.tmpmax[g][0][c], u.ph1.tmpmax[g][1][c]);
    }
    __syncthreads();

    // ---- a1 = relu(bn1(xp)) ----
    for (int r = 0; r < 4; r++) {
        int idx = t + 256 * r;
        int c = idx >> 3, pp = idx & 7;
        float sc = bn1[c] * rsqrtf(bn1[384 + c] + 1e-5f);
        float v = (xp[c][pp] - bn1[256 + c]) * sc + bn1[128 + c];
        a1y[c][pp] = fmaxf(v, 0.f);
    }

    // ---- c1: h1[o][p] = c1_b[o] + sum_c a1[c][p]*c1w[o][c], o in 0..63 ----
    const int p = t & 7;
    const int o0 = t >> 3;   // 0..31
    float acc0 = c1b[o0], acc1 = c1b[o0 + 32];
    for (int c0 = 0; c0 < 128; c0 += 32) {
        __syncthreads();   // also covers a1y-written / tmpmax->wbuf reuse
#pragma unroll
        for (int r = 0; r < 8; r++) {
            int idx = r * 256 + t;
            int cc = idx & 31, o = idx >> 5;
            u.wbuf[cc * 65 + o] = c1w[o * 128 + c0 + cc];
        }
        __syncthreads();
#pragma unroll
        for (int c = 0; c < 32; c++) {
            float av = a1y[c0 + c][p];
            acc0 += av * u.wbuf[c * 65 + o0];
            acc1 += av * u.wbuf[c * 65 + o0 + 32];
        }
    }
    h1s[o0][p] = acc0;
    h1s[o0 + 32][p] = acc1;
    __syncthreads();

    // ---- a2 = relu(bn2(h1)) into padded ap ----
    if (t < 128) ap[t >> 1][(t & 1) * 9] = 0.f;
    for (int r = 0; r < 2; r++) {
        int idx = t + 256 * r;
        int i = idx >> 3, pp = idx & 7;
        float sc = bn2[i] * rsqrtf(bn2[192 + i] + 1e-5f);
        float v = (h1s[i][pp] - bn2[128 + i]) * sc + bn2[64 + i];
        ap[i][pp + 1] = fmaxf(v, 0.f);
    }

    // ---- c2: conv3 over p, 64->64 ----
    float d0 = c2b[o0], d1 = c2b[o0 + 32];
    for (int i0 = 0; i0 < 64; i0 += 16) {
        __syncthreads();
#pragma unroll
        for (int r = 0; r < 12; r++) {
            int idx = r * 256 + t;
            int o = idx / 48, rem = idx % 48;
            u.wbuf[rem * 65 + o] = c2w[o * 192 + i0 * 3 + rem];
        }
        __syncthreads();
#pragma unroll
        for (int ii = 0; ii < 16; ii++) {
            float a_0 = ap[i0 + ii][p];
            float a_1 = ap[i0 + ii][p + 1];
            float a_2 = ap[i0 + ii][p + 2];
            d0 += a_0 * u.wbuf[(ii * 3 + 0) * 65 + o0]
                + a_1 * u.wbuf[(ii * 3 + 1) * 65 + o0]
                + a_2 * u.wbuf[(ii * 3 + 2) * 65 + o0];
            d1 += a_0 * u.wbuf[(ii * 3 + 0) * 65 + o0 + 32]
                + a_1 * u.wbuf[(ii * 3 + 1) * 65 + o0 + 32]
                + a_2 * u.wbuf[(ii * 3 + 2) * 65 + o0 + 32];
        }
    }
    h2s[o0][p] = d0;
    h2s[o0 + 32][p] = d1;
    __syncthreads();

    // ---- a3 = relu(bn3(h2)) ----
    for (int r = 0; r < 2; r++) {
        int idx = t + 256 * r;
        int i = idx >> 3, pp = idx & 7;
        float sc = bn3[i] * rsqrtf(bn3[192 + i] + 1e-5f);
        float v = (h2s[i][pp] - bn3[128 + i]) * sc + bn3[64 + i];
        a3s[i][pp] = fmaxf(v, 0.f);
    }

    // ---- c3: 64->128 + residual, y into a1y ----
    for (int it = 0; it < 4; it++) {
        __syncthreads();   // covers a3s written + previous wbuf reads done
#pragma unroll
        for (int r = 0; r < 8; r++) {
            int idx = r * 256 + t;
            int i = idx & 63, oo = idx >> 6;
            u.wbuf[i * 33 + oo] = c3w[(it * 32 + oo) * 64 + i];
        }
        __syncthreads();
        int o = it * 32 + o0;
        float acc = c3b[o];
#pragma unroll
        for (int i = 0; i < 64; i++) acc += a3s[i][p] * u.wbuf[i * 33 + o0];
        a1y[o][p] = xp[o][p] + acc;
    }
    __syncthreads();

    // ---- fc2: logits[j] = b + sum relu(yflat)*wfc2[j], softmax ----
    const float* yflat = &a1y[0][0];
    float pj0 = 0.f, pj1 = 0.f, pj2 = 0.f, pj3 = 0.f;
#pragma unroll
    for (int r = 0; r < 4; r++) {
        int f = t + 256 * r;
        float v = fmaxf(yflat[f], 0.f);
        pj0 += v * wfc2[f];
        pj1 += v * wfc2[1024 + f];
        pj2 += v * wfc2[2048 + f];
        pj3 += v * wfc2[3072 + f];
    }
#pragma unroll
    for (int off = 32; off > 0; off >>= 1) {
        pj0 += __shfl_down(pj0, off, 64);
        pj1 += __shfl_down(pj1, off, 64);
        pj2 += __shfl_down(pj2, off, 64);
        pj3 += __shfl_down(pj3, off, 64);
    }
    if ((t & 63) == 0) {
        int w = t >> 6;
        red[w * 4 + 0] = pj0; red[w * 4 + 1] = pj1;
        red[w * 4 + 2] = pj2; red[w * 4 + 3] = pj3;
    }
    __syncthreads();
    if (t == 0) {
        float lg[4];
#pragma unroll
        for (int j = 0; j < 4; j++)
            lg[j] = bfc2[j] + red[j] + red[4 + j] + red[8 + j] + red[12 + j];
        float mx = fmaxf(fmaxf(lg[0], lg[1]), fmaxf(lg[2], lg[3]));
        float e0 = expf(lg[0] - mx), e1 = expf(lg[1] - mx);
        float e2 = expf(lg[2] - mx), e3 = expf(lg[3] - mx);
        float s = e0 + e1 + e2 + e3;
        out[n * 4 + 0] = e0 / s;
        out[n * 4 + 1] = e1 / s;
        out[n * 4 + 2] = e2 / s;
        out[n * 4 + 3] = e3 / s;
    }
}

extern "C" void kernel_launch(void* const* d_in, const int* in_sizes, int n_in,
                              void* d_out, int out_size, void* d_ws, size_t ws_size,
                              hipStream_t stream) {
    const float* feature = (const float*)d_in[0];
    const float* lines   = (const float*)d_in[1];
    const float* w_fc1   = (const float*)d_in[2];
    const float* b_fc1   = (const float*)d_in[3];
    const float* bn1     = (const float*)d_in[4];
    const float* c1_w    = (const float*)d_in[5];
    const float* c1_b    = (const float*)d_in[6];
    const float* bn2     = (const float*)d_in[7];
    const float* c2_w    = (const float*)d_in[8];
    const float* c2_b    = (const float*)d_in[9];
    const float* bn3     = (const float*)d_in[10];
    const float* c3_w    = (const float*)d_in[11];
    const float* c3_b    = (const float*)d_in[12];
    const float* w_fc2   = (const float*)d_in[13];
    const float* b_fc2   = (const float*)d_in[14];
    float* out = (float*)d_out;

    float* x   = (float*)d_ws;          // [2, 65536, 128] = 67,108,864 B
    float* w_t = x + (size_t)2 * HW * DLOI;  // [256, 128] = 131,072 B

    transpose_w_kernel<<<128, 256, 0, stream>>>(w_fc1, w_t);
    fc1_kernel<<<1024, 256, 0, stream>>>(feature, w_t, b_fc1, x);
    line_kernel<<<NLINES, 256, 0, stream>>>(x, lines, bn1, c1_w, c1_b, bn2,
                                            c2_w, c2_b, bn3, c3_w, c3_b,
                                            w_fc2, b_fc2, out);
}

// Round 2
// 385.464 us; speedup vs baseline: 1.6875x; 1.6875x over previous
//
#include <hip/hip_runtime.h>
#include <math.h>
#include <stdint.h>

#define HH 256
#define HW 65536
#define CIN 256
#define DLOI 128
#define NLINES 10000
#define LPB 5000

typedef _Float16 h2v  __attribute__((ext_vector_type(2)));
typedef _Float16 f16x8 __attribute__((ext_vector_type(8)));
typedef float    f32x4 __attribute__((ext_vector_type(4)));

__device__ __forceinline__ h2v u2h(unsigned int u) { return __builtin_bit_cast(h2v, u); }
__device__ __forceinline__ unsigned int h2u(h2v h) { return __builtin_bit_cast(unsigned int, h); }

// f16 pair dot with fp32 accumulate: v_dot2_f32_f16
__device__ __forceinline__ float fdot2(h2v a, unsigned int w, float c) {
#if __has_builtin(__builtin_amdgcn_fdot2)
    return __builtin_amdgcn_fdot2(a, u2h(w), c, false);
#else
    h2v b = u2h(w);
    return c + (float)a[0] * (float)b[0] + (float)a[1] * (float)b[1];
#endif
}

__device__ __forceinline__ h2v relu2(h2v a) {
    h2v z = (h2v)(_Float16)0.f;
#if __has_builtin(__builtin_elementwise_max)
    return __builtin_elementwise_max(a, z);
#else
    h2v r; r[0] = a[0] > z[0] ? a[0] : z[0]; r[1] = a[1] > z[1] ? a[1] : z[1]; return r;
#endif
}
__device__ __forceinline__ h2v hmax2v(h2v a, h2v b) {
#if __has_builtin(__builtin_elementwise_max)
    return __builtin_elementwise_max(a, b);
#else
    h2v r; r[0] = a[0] > b[0] ? a[0] : b[0]; r[1] = a[1] > b[1] ? a[1] : b[1]; return r;
#endif
}

// ---------------------------------------------------------------------------
// prep_small: f16 conversions of all small weights (RTN via _Float16 cast),
// paired over input channels for v_dot2, plus folded BN scale/shift packs.
// ---------------------------------------------------------------------------
__global__ __launch_bounds__(256) void prep_small(
    const float* __restrict__ w_fc1, const float* __restrict__ c1w,
    const float* __restrict__ c2w,  const float* __restrict__ c3w,
    const float* __restrict__ wfc2, const float* __restrict__ bn1,
    const float* __restrict__ bn2,  const float* __restrict__ bn3,
    _Float16* __restrict__ wf16, unsigned int* __restrict__ c1w16,
    unsigned int* __restrict__ c2w16, unsigned int* __restrict__ c3w16,
    unsigned int* __restrict__ wfc2_16, unsigned int* __restrict__ bn_pk)
{
    int i = blockIdx.x * 256 + threadIdx.x;
    if (i < 32768) { wf16[i] = (_Float16)w_fc1[i]; return; }
    i -= 32768;
    if (i < 4096) {                       // c1w16[c2][o]
        int c2 = i >> 6, o = i & 63;
        h2v v = { (_Float16)c1w[o * 128 + 2 * c2], (_Float16)c1w[o * 128 + 2 * c2 + 1] };
        c1w16[c2 * 64 + o] = h2u(v); return;
    }
    i -= 4096;
    if (i < 6144) {                       // c2w16[i2][tap][o]
        int o = i & 63, rem = i >> 6; int tap = rem % 3, i2 = rem / 3;
        h2v v = { (_Float16)c2w[(o * 64 + 2 * i2) * 3 + tap],
                  (_Float16)c2w[(o * 64 + 2 * i2 + 1) * 3 + tap] };
        c2w16[(i2 * 3 + tap) * 64 + o] = h2u(v); return;
    }
    i -= 6144;
    if (i < 4096) {                       // c3w16[i2][o]
        int o = i & 127, i2 = i >> 7;
        h2v v = { (_Float16)c3w[o * 64 + 2 * i2], (_Float16)c3w[o * 64 + 2 * i2 + 1] };
        c3w16[i2 * 128 + o] = h2u(v); return;
    }
    i -= 4096;
    if (i < 2048) {                       // wfc2_16[j][c2][p], f = c*8+p
        int p = i & 7, c2 = (i >> 3) & 63, j = i >> 9;
        h2v v = { (_Float16)wfc2[j * 1024 + (2 * c2) * 8 + p],
                  (_Float16)wfc2[j * 1024 + (2 * c2 + 1) * 8 + p] };
        wfc2_16[j * 512 + c2 * 8 + p] = h2u(v); return;
    }
    i -= 2048;
    if (i < 128) {                        // bn packs: scale, shift = beta - mean*scale
        const float* bn; int C, base, hcount;
        if (i < 64)      { bn = bn1; C = 128; base = 0;   hcount = 64; }
        else if (i < 96) { bn = bn2; C = 64;  base = 128; hcount = 32; i -= 64; }
        else             { bn = bn3; C = 64;  base = 192; hcount = 32; i -= 96; }
        int c0 = 2 * i, c1 = 2 * i + 1;
        float s0 = bn[c0] * rsqrtf(bn[3 * C + c0] + 1e-5f);
        float s1 = bn[c1] * rsqrtf(bn[3 * C + c1] + 1e-5f);
        float h0 = bn[C + c0] - bn[2 * C + c0] * s0;
        float h1 = bn[C + c1] - bn[2 * C + c1] * s1;
        h2v sv = { (_Float16)s0, (_Float16)s1 };
        h2v hv = { (_Float16)h0, (_Float16)h1 };
        bn_pk[base + i] = h2u(sv);
        bn_pk[base + hcount + i] = h2u(hv);
    }
}

// ---------------------------------------------------------------------------
// transpose_feat: feature [B,CIN,HW] f32 -> A [B*HW][CIN] f16 (K-contiguous
// per pixel, the MFMA B-operand layout). 64x64 tiles via LDS.
// ---------------------------------------------------------------------------
__global__ __launch_bounds__(256) void transpose_feat(
    const float* __restrict__ feat, unsigned int* __restrict__ A)
{
    __shared__ float T[64][65];
    const int t = threadIdx.x;
    const int bi = blockIdx.x;                  // 2 * 1024 * 4
    const int ct = bi & 3, pt = (bi >> 2) & 1023, b = bi >> 12;
    const int c0 = ct * 64, pix0 = pt * 64;
    const float* src = feat + ((size_t)(b * 256 + c0)) * 65536 + pix0;
    for (int r = 0; r < 16; r++) {
        int idx = r * 256 + t; int ci = idx >> 6, q = idx & 63;
        T[ci][q] = src[(size_t)ci * 65536 + q];
    }
    __syncthreads();
    unsigned int* dst = A + ((size_t)(b * 65536 + pix0)) * 128 + c0 / 2;
    for (int r = 0; r < 8; r++) {
        int q = r * 8 + (t >> 5); int i2 = t & 31;
        h2v v = { (_Float16)T[2 * i2][q], (_Float16)T[2 * i2 + 1][q] };
        dst[(size_t)q * 128 + i2] = h2u(v);
    }
}

// ---------------------------------------------------------------------------
// fc1 via f16 MFMA: X[pix][o] = sum_c A[pix][c]*W[o][c] + bias[o], stored f16.
// M=o(128), N=pix(128) per block, K=256 in 8 steps of 32. 16x16x32 tiles.
// ---------------------------------------------------------------------------
__global__ __launch_bounds__(256, 4) void fc1_mfma(
    const _Float16* __restrict__ W,   // [128][256] f16
    const _Float16* __restrict__ A,   // [131072][256] f16
    const float* __restrict__ bias,
    unsigned int* __restrict__ X)     // [131072][64] h2 units
{
    __shared__ _Float16 Wl[128 * 32];
    __shared__ _Float16 Fl[128 * 32];
    const int t = threadIdx.x;
    const int lane = t & 63, wave = t >> 6;
    const int wm = wave & 1, wn = wave >> 1;
    const int pix0 = blockIdx.x * 128;

    f32x4 acc[4][4];
    for (int a = 0; a < 4; a++)
        for (int b = 0; b < 4; b++) acc[a][b] = (f32x4)0.f;

    for (int ks = 0; ks < 8; ks++) {
        const int k0 = ks * 32;
        __syncthreads();
#pragma unroll
        for (int cc = 0; cc < 2; cc++) {
            int ch = t + cc * 256;                // 512 16B-chunks per matrix
            int row = ch >> 2, ko = (ch & 3) * 8;
            *(uint4*)&Wl[row * 32 + ko] = *(const uint4*)(W + row * 256 + k0 + ko);
            *(uint4*)&Fl[row * 32 + ko] =
                *(const uint4*)(A + (size_t)(pix0 + row) * 256 + k0 + ko);
        }
        __syncthreads();
        f16x8 af[4], bf[4];
#pragma unroll
        for (int mt = 0; mt < 4; mt++)
            af[mt] = *(const f16x8*)&Wl[(wm * 64 + mt * 16 + (lane & 15)) * 32 + (lane >> 4) * 8];
#pragma unroll
        for (int nt = 0; nt < 4; nt++)
            bf[nt] = *(const f16x8*)&Fl[(wn * 64 + nt * 16 + (lane & 15)) * 32 + (lane >> 4) * 8];
#pragma unroll
        for (int mt = 0; mt < 4; mt++)
#pragma unroll
            for (int nt = 0; nt < 4; nt++)
                acc[mt][nt] = __builtin_amdgcn_mfma_f32_16x16x32_f16(af[mt], bf[nt], acc[mt][nt], 0, 0, 0);
    }
#pragma unroll
    for (int mt = 0; mt < 4; mt++) {
        int o = wm * 64 + mt * 16 + (lane >> 4) * 4;
        float4 b4 = *(const float4*)(bias + o);
#pragma unroll
        for (int nt = 0; nt < 4; nt++) {
            int pix = pix0 + wn * 64 + nt * 16 + (lane & 15);
            f32x4 a = acc[mt][nt];
            h2v lo = { (_Float16)(a[0] + b4.x), (_Float16)(a[1] + b4.y) };
            h2v hi = { (_Float16)(a[2] + b4.z), (_Float16)(a[3] + b4.w) };
            uint2 v = { h2u(lo), h2u(hi) };
            *(uint2*)(X + (size_t)pix * 64 + (o >> 1)) = v;
        }
    }
}

// ---------------------------------------------------------------------------
// line_v2: 8 lines per block. f16 activations in LDS (padded strides),
// v_dot2_f32_f16 GEMMs with scalar-loaded weights, 8 syncs total.
// ---------------------------------------------------------------------------
__global__ __launch_bounds__(256, 3) void line_v2(
    const unsigned int* __restrict__ X,      // [131072][64] h2 units
    const float* __restrict__ lines,
    const unsigned int* __restrict__ c1w16, const float* __restrict__ c1b,
    const unsigned int* __restrict__ c2w16, const float* __restrict__ c2b,
    const unsigned int* __restrict__ c3w16, const float* __restrict__ c3b,
    const unsigned int* __restrict__ wfc2_16, const float* __restrict__ bfc2,
    const unsigned int* __restrict__ bn_pk,
    float* __restrict__ out)
{
    __shared__ int geoB[256];
    __shared__ unsigned int geoWA[256], geoWB[256];
    __shared__ h2v xp[64 * 65];   // [c2][col], col = line*8 + p
    __shared__ h2v yb[64 * 65];   // a1, later y
    __shared__ h2v hb[32 * 65];   // h1, later h2out
    __shared__ h2v ap[32 * 73];   // a2 padded (stride 9/line), later a3 [32][64]

    const int t = threadIdx.x;
    const int n0 = blockIdx.x * 8;
    const int col = t & 63;
    const int og = t >> 6;

    // ---- phase 1: geometry for 256 sample points ----
    {
        int l = t >> 5, k = t & 31;
        int n = n0 + l;
        float4 ln = *(const float4*)(lines + n * 4);
        float lam = (float)k / 31.0f;
        float px = ln.x * lam + ln.z * (1.f - lam) - 0.5f;
        float py = ln.y * lam + ln.w * (1.f - lam) - 0.5f;
        float px0 = fminf(fmaxf(floorf(px), 0.f), 255.f);
        float py0 = fminf(fmaxf(floorf(py), 0.f), 255.f);
        float dx = px - px0, dy = py - py0;      // px1=px0+1 always (px<=254.5)
        float ex = 1.f - dx, ey = 1.f - dy;
        h2v wA = { (_Float16)(ex * ey), (_Float16)(dx * ey) };
        h2v wB = { (_Float16)(ex * dy), (_Float16)(dx * dy) };
        int b = (n >= LPB) ? 1 : 0;
        int pixflat = (b << 16) + ((int)px0 << 8) + (int)py0;
        geoB[t] = pixflat << 6;                  // h2-index
        geoWA[t] = h2u(wA); geoWB[t] = h2u(wB);
    }
    __syncthreads();

    // ---- phase 2: bilinear gather (f16) + maxpool4 -> xp ----
    {
        const int c2 = t & 63;
        const int g0 = t >> 6;
        const h2v* xh = (const h2v*)X;
#pragma unroll
        for (int l = 0; l < 8; l++) {
#pragma unroll
            for (int gi = 0; gi < 2; gi++) {
                int g = g0 + gi * 4;
                int ptb = l * 32 + g * 4;
                h2v m;
#pragma unroll
                for (int s = 0; s < 4; s++) {
                    int pt = ptb + s;
                    int base = geoB[pt] + c2;
                    h2v wA = u2h(geoWA[pt]), wB = u2h(geoWB[pt]);
                    h2v x00 = xh[base], x10 = xh[base + 16384];
                    h2v x01 = xh[base + 64], x11 = xh[base + 16448];
                    h2v w00 = { wA[0], wA[0] }, w10 = { wA[1], wA[1] };
                    h2v w01 = { wB[0], wB[0] }, w11 = { wB[1], wB[1] };
                    h2v v = x00 * w00 + x10 * w10 + x01 * w01 + x11 * w11;
                    m = (s == 0) ? v : hmax2v(m, v);
                }
                xp[c2 * 65 + l * 8 + g] = m;
            }
        }
    }
    __syncthreads();

    // ---- phase 3: a1 = relu(bn1(xp)) ----
#pragma unroll
    for (int r = 0; r < 16; r++) {
        int c2 = og + r * 4;
        h2v sc = u2h(bn_pk[c2]), sh = u2h(bn_pk[64 + c2]);
        yb[c2 * 65 + col] = relu2(xp[c2 * 65 + col] * sc + sh);
    }
    __syncthreads();

    // ---- phase 4: c1 (128->64), scalar weights ----
    {
        const int obU = __builtin_amdgcn_readfirstlane(og * 16);
        float acc[16];
#pragma unroll
        for (int i = 0; i < 16; i++) acc[i] = c1b[obU + i];
#pragma unroll 8
        for (int c2 = 0; c2 < 64; c2++) {
            h2v av = yb[c2 * 65 + col];
            unsigned int wv[16];
#pragma unroll
            for (int q = 0; q < 4; q++)
                *(uint4*)&wv[q * 4] = *(const uint4*)(c1w16 + c2 * 64 + obU + q * 4);
#pragma unroll
            for (int i = 0; i < 16; i++) acc[i] = fdot2(av, wv[i], acc[i]);
        }
#pragma unroll
        for (int j = 0; j < 8; j++) {
            h2v v = { (_Float16)acc[2 * j], (_Float16)acc[2 * j + 1] };
            hb[(obU / 2 + j) * 65 + col] = v;
        }
    }
    __syncthreads();

    // ---- phase 5: a2 = relu(bn2(h1)) into padded ap (stride 9/line) ----
    {
        int c2 = t >> 3, l = t & 7;
        h2v sc = u2h(bn_pk[128 + c2]), sh = u2h(bn_pk[160 + c2]);
        h2v z = (h2v)(_Float16)0.f;
        ap[c2 * 73 + l * 9] = z;
#pragma unroll
        for (int p = 0; p < 8; p++)
            ap[c2 * 73 + l * 9 + 1 + p] = relu2(hb[c2 * 65 + l * 8 + p] * sc + sh);
        if (l == 7) ap[c2 * 73 + 72] = z;
    }
    __syncthreads();

    // ---- phase 6: c2 conv3 (64->64) ----
    {
        const int obU = __builtin_amdgcn_readfirstlane(og * 16);
        const int l = col >> 3, p = col & 7;
        const int pos0 = l * 9 + p;
        float acc[16];
#pragma unroll
        for (int i = 0; i < 16; i++) acc[i] = c2b[obU + i];
#pragma unroll 2
        for (int i2 = 0; i2 < 32; i2++) {
            h2v a0 = ap[i2 * 73 + pos0];
            h2v a1 = ap[i2 * 73 + pos0 + 1];
            h2v a2 = ap[i2 * 73 + pos0 + 2];
            unsigned int wv[48];
#pragma unroll
            for (int tap = 0; tap < 3; tap++)
#pragma unroll
                for (int q = 0; q < 4; q++)
                    *(uint4*)&wv[tap * 16 + q * 4] =
                        *(const uint4*)(c2w16 + (i2 * 3 + tap) * 64 + obU + q * 4);
#pragma unroll
            for (int i = 0; i < 16; i++) {
                acc[i] = fdot2(a0, wv[i], acc[i]);
                acc[i] = fdot2(a1, wv[16 + i], acc[i]);
                acc[i] = fdot2(a2, wv[32 + i], acc[i]);
            }
        }
#pragma unroll
        for (int j = 0; j < 8; j++) {
            h2v v = { (_Float16)acc[2 * j], (_Float16)acc[2 * j + 1] };
            hb[(obU / 2 + j) * 65 + col] = v;
        }
    }
    __syncthreads();

    // ---- phase 7: a3 = relu(bn3(h2)) into ap[0..2047] ----
#pragma unroll
    for (int r = 0; r < 8; r++) {
        int idx = t + 256 * r;
        int c2 = idx >> 6, cl = idx & 63;
        h2v sc = u2h(bn_pk[192 + c2]), sh = u2h(bn_pk[224 + c2]);
        ap[c2 * 64 + cl] = relu2(hb[c2 * 65 + cl] * sc + sh);
    }
    __syncthreads();

    // ---- phase 8: c3 (64->128) + residual -> y ----
    {
        const int obU = __builtin_amdgcn_readfirstlane(og * 32);
        float acc[32];
#pragma unroll
        for (int i = 0; i < 32; i++) acc[i] = c3b[obU + i];
#pragma unroll 2
        for (int i2 = 0; i2 < 32; i2++) {
            h2v av = ap[i2 * 64 + col];
            unsigned int wv[32];
#pragma unroll
            for (int q = 0; q < 8; q++)
                *(uint4*)&wv[q * 4] = *(const uint4*)(c3w16 + i2 * 128 + obU + q * 4);
#pragma unroll
            for (int i = 0; i < 32; i++) acc[i] = fdot2(av, wv[i], acc[i]);
        }
#pragma unroll
        for (int j = 0; j < 16; j++) {
            h2v hv = { (_Float16)acc[2 * j], (_Float16)acc[2 * j + 1] };
            yb[(obU / 2 + j) * 65 + col] = xp[(obU / 2 + j) * 65 + col] + hv;
        }
    }
    __syncthreads();

    // ---- phase 9: fc2 + softmax ----
    {
        int l = t >> 5, q = t & 31;
        float aj[4] = { 0.f, 0.f, 0.f, 0.f };
#pragma unroll
        for (int hf = 0; hf < 2; hf++) {
            int c2 = q + 32 * hf;
            h2v yv[8];
#pragma unroll
            for (int p = 0; p < 8; p++) yv[p] = relu2(yb[c2 * 65 + l * 8 + p]);
#pragma unroll
            for (int j = 0; j < 4; j++) {
                unsigned int wv[8];
                *(uint4*)&wv[0] = *(const uint4*)(wfc2_16 + j * 512 + c2 * 8);
                *(uint4*)&wv[4] = *(const uint4*)(wfc2_16 + j * 512 + c2 * 8 + 4);
#pragma unroll
                for (int p = 0; p < 8; p++) aj[j] = fdot2(yv[p], wv[p], aj[j]);
            }
        }
#pragma unroll
        for (int off = 16; off > 0; off >>= 1) {
#pragma unroll
            for (int j = 0; j < 4; j++) aj[j] += __shfl_down(aj[j], off, 32);
        }
        if (q == 0) {
            float lg0 = aj[0] + bfc2[0], lg1 = aj[1] + bfc2[1];
            float lg2 = aj[2] + bfc2[2], lg3 = aj[3] + bfc2[3];
            float mx = fmaxf(fmaxf(lg0, lg1), fmaxf(lg2, lg3));
            float e0 = expf(lg0 - mx), e1 = expf(lg1 - mx);
            float e2 = expf(lg2 - mx), e3 = expf(lg3 - mx);
            float s = 1.f / (e0 + e1 + e2 + e3);
            float4 r = { e0 * s, e1 * s, e2 * s, e3 * s };
            *(float4*)(out + (size_t)(n0 + l) * 4) = r;
        }
    }
}

extern "C" void kernel_launch(void* const* d_in, const int* in_sizes, int n_in,
                              void* d_out, int out_size, void* d_ws, size_t ws_size,
                              hipStream_t stream) {
    const float* feature = (const float*)d_in[0];
    const float* lines   = (const float*)d_in[1];
    const float* w_fc1   = (const float*)d_in[2];
    const float* b_fc1   = (const float*)d_in[3];
    const float* bn1     = (const float*)d_in[4];
    const float* c1_w    = (const float*)d_in[5];
    const float* c1_b    = (const float*)d_in[6];
    const float* bn2     = (const float*)d_in[7];
    const float* c2_w    = (const float*)d_in[8];
    const float* c2_b    = (const float*)d_in[9];
    const float* bn3     = (const float*)d_in[10];
    const float* c3_w    = (const float*)d_in[11];
    const float* c3_b    = (const float*)d_in[12];
    const float* w_fc2   = (const float*)d_in[13];
    const float* b_fc2   = (const float*)d_in[14];
    float* out = (float*)d_out;

    char* ws = (char*)d_ws;
    unsigned int* X       = (unsigned int*)ws;                   // 33,554,432 B
    _Float16*     A       = (_Float16*)(ws + 33554432);          // 67,108,864 B
    _Float16*     wf16    = (_Float16*)(ws + 100663296);         // 65,536 B
    unsigned int* c1w16   = (unsigned int*)(ws + 100728832);     // 16,384 B
    unsigned int* c2w16   = (unsigned int*)(ws + 100745216);     // 24,576 B
    unsigned int* c3w16   = (unsigned int*)(ws + 100769792);     // 16,384 B
    unsigned int* wfc2_16 = (unsigned int*)(ws + 100786176);     // 8,192 B
    unsigned int* bn_pk   = (unsigned int*)(ws + 100794368);     // 1,024 B

    prep_small<<<193, 256, 0, stream>>>(w_fc1, c1_w, c2_w, c3_w, w_fc2, bn1, bn2, bn3,
                                        wf16, c1w16, c2w16, c3w16, wfc2_16, bn_pk);
    transpose_feat<<<8192, 256, 0, stream>>>(feature, (unsigned int*)A);
    fc1_mfma<<<1024, 256, 0, stream>>>(wf16, A, b_fc1, X);
    line_v2<<<1250, 256, 0, stream>>>(X, lines, c1w16, c1_b, c2w16, c2_b,
                                      c3w16, c3_b, wfc2_16, b_fc2, bn_pk, out);
}

// Round 3
// 313.711 us; speedup vs baseline: 2.0735x; 1.2287x over previous
//
#include <hip/hip_runtime.h>
#include <math.h>
#include <stdint.h>

#define HH 256
#define HW 65536
#define CIN 256
#define DLOI 128
#define NLINES 10000
#define LPB 5000

typedef _Float16 h2v  __attribute__((ext_vector_type(2)));
typedef _Float16 f16x8 __attribute__((ext_vector_type(8)));
typedef float    f32x4 __attribute__((ext_vector_type(4)));

__device__ __forceinline__ h2v u2h(unsigned int u) { return __builtin_bit_cast(h2v, u); }
__device__ __forceinline__ unsigned int h2u(h2v h) { return __builtin_bit_cast(unsigned int, h); }

__device__ __forceinline__ float fdot2(h2v a, unsigned int w, float c) {
#if __has_builtin(__builtin_amdgcn_fdot2)
    return __builtin_amdgcn_fdot2(a, u2h(w), c, false);
#else
    h2v b = u2h(w);
    return c + (float)a[0] * (float)b[0] + (float)a[1] * (float)b[1];
#endif
}

__device__ __forceinline__ h2v relu2(h2v a) {
    h2v z = (h2v)(_Float16)0.f;
#if __has_builtin(__builtin_elementwise_max)
    return __builtin_elementwise_max(a, z);
#else
    h2v r; r[0] = a[0] > z[0] ? a[0] : z[0]; r[1] = a[1] > z[1] ? a[1] : z[1]; return r;
#endif
}
__device__ __forceinline__ h2v hmax2v(h2v a, h2v b) {
#if __has_builtin(__builtin_elementwise_max)
    return __builtin_elementwise_max(a, b);
#else
    h2v r; r[0] = a[0] > b[0] ? a[0] : b[0]; r[1] = a[1] > b[1] ? a[1] : b[1]; return r;
#endif
}

// ---------------------------------------------------------------------------
// prep_small: f16 weight conversions + folded BN packs.
// ---------------------------------------------------------------------------
__global__ __launch_bounds__(256) void prep_small(
    const float* __restrict__ w_fc1, const float* __restrict__ c1w,
    const float* __restrict__ c2w,  const float* __restrict__ c3w,
    const float* __restrict__ wfc2, const float* __restrict__ bn1,
    const float* __restrict__ bn2,  const float* __restrict__ bn3,
    _Float16* __restrict__ wf16, unsigned int* __restrict__ c1w16,
    unsigned int* __restrict__ c2w16, unsigned int* __restrict__ c3w16,
    unsigned int* __restrict__ wfc2p, unsigned int* __restrict__ bn_pk)
{
    int i = blockIdx.x * 256 + threadIdx.x;
    if (i < 32768) { wf16[i] = (_Float16)w_fc1[i]; return; }
    i -= 32768;
    if (i < 4096) {                       // c1w16[c2][o]
        int c2 = i >> 6, o = i & 63;
        h2v v = { (_Float16)c1w[o * 128 + 2 * c2], (_Float16)c1w[o * 128 + 2 * c2 + 1] };
        c1w16[c2 * 64 + o] = h2u(v); return;
    }
    i -= 4096;
    if (i < 6144) {                       // c2w16[i2][tap][o]
        int o = i & 63, rem = i >> 6; int tap = rem % 3, i2 = rem / 3;
        h2v v = { (_Float16)c2w[(o * 64 + 2 * i2) * 3 + tap],
                  (_Float16)c2w[(o * 64 + 2 * i2 + 1) * 3 + tap] };
        c2w16[(i2 * 3 + tap) * 64 + o] = h2u(v); return;
    }
    i -= 6144;
    if (i < 4096) {                       // c3w16[i2][o]
        int o = i & 127, i2 = i >> 7;
        h2v v = { (_Float16)c3w[o * 64 + 2 * i2], (_Float16)c3w[o * 64 + 2 * i2 + 1] };
        c3w16[i2 * 128 + o] = h2u(v); return;
    }
    i -= 4096;
    if (i < 2048) {                       // wfc2p[(j*8+p)*64 + c2]
        int c2 = i & 63, p = (i >> 6) & 7, j = i >> 9;
        h2v v = { (_Float16)wfc2[j * 1024 + (2 * c2) * 8 + p],
                  (_Float16)wfc2[j * 1024 + (2 * c2 + 1) * 8 + p] };
        wfc2p[(j * 8 + p) * 64 + c2] = h2u(v); return;
    }
    i -= 2048;
    if (i < 128) {                        // bn packs: scale, shift = beta - mean*scale
        const float* bn; int C, base, hcount;
        if (i < 64)      { bn = bn1; C = 128; base = 0;   hcount = 64; }
        else if (i < 96) { bn = bn2; C = 64;  base = 128; hcount = 32; i -= 64; }
        else             { bn = bn3; C = 64;  base = 192; hcount = 32; i -= 96; }
        int c0 = 2 * i, c1 = 2 * i + 1;
        float s0 = bn[c0] * rsqrtf(bn[3 * C + c0] + 1e-5f);
        float s1 = bn[c1] * rsqrtf(bn[3 * C + c1] + 1e-5f);
        float h0 = bn[C + c0] - bn[2 * C + c0] * s0;
        float h1 = bn[C + c1] - bn[2 * C + c1] * s1;
        h2v sv = { (_Float16)s0, (_Float16)s1 };
        h2v hv = { (_Float16)h0, (_Float16)h1 };
        bn_pk[base + i] = h2u(sv);
        bn_pk[base + hcount + i] = h2u(hv);
    }
}

// ---------------------------------------------------------------------------
// fc1_fused: reads f32 feature [B,C,pix] directly (no pre-transpose pass),
// stages f32 tile in LDS, converts to f16 during fragment build, f16 MFMA,
// writes X [pix][64 h2]. 128 pix x 128 o per block, K=256 in 8 steps.
// ---------------------------------------------------------------------------
__global__ __launch_bounds__(256, 4) void fc1_fused(
    const float* __restrict__ feat,   // [B,256,65536]
    const _Float16* __restrict__ W,   // [128][256] f16
    const float* __restrict__ bias,
    unsigned int* __restrict__ X)     // [131072][64] h2 units
{
    __shared__ float Tf[32 * 132];    // f32 feature tile [c][pix], pad 132
    __shared__ _Float16 Wl[128 * 40]; // f16 W tile [o][k], pad 40
    const int t = threadIdx.x;
    const int lane = t & 63, wave = t >> 6;
    const int wm = wave & 1, wn = wave >> 1;
    const int pix0g = blockIdx.x << 7;              // global pixel base
    const int b = blockIdx.x >> 9;
    const int pix0l = pix0g & 65535;                // within batch
    const float* fbase = feat + (size_t)b * (256u * 65536u) + pix0l;

    f32x4 acc[4][4];
#pragma unroll
    for (int a = 0; a < 4; a++)
#pragma unroll
        for (int c = 0; c < 4; c++) acc[a][c] = (f32x4)0.f;

    for (int ks = 0; ks < 8; ks++) {
        const int k0 = ks * 32;
        __syncthreads();
#pragma unroll
        for (int r = 0; r < 4; r++) {               // 32 c x 128 pix f32
            int idx = t + r * 256;
            int c = idx >> 5, p4 = idx & 31;
            float4 v = *(const float4*)(fbase + (size_t)(k0 + c) * 65536 + p4 * 4);
            *(float4*)&Tf[c * 132 + p4 * 4] = v;
        }
#pragma unroll
        for (int r = 0; r < 2; r++) {               // 128 o x 32 k f16
            int idx = t + r * 256;
            int row = idx >> 2, ko = (idx & 3) * 8;
            *(uint4*)&Wl[row * 40 + ko] = *(const uint4*)(W + row * 256 + k0 + ko);
        }
        __syncthreads();
        f16x8 af[4], bf[4];
#pragma unroll
        for (int mt = 0; mt < 4; mt++)
            af[mt] = *(const f16x8*)&Wl[(wm * 64 + mt * 16 + (lane & 15)) * 40 + (lane >> 4) * 8];
#pragma unroll
        for (int nt = 0; nt < 4; nt++) {
            int q = wn * 64 + nt * 16 + (lane & 15);
            int cb = (lane >> 4) * 8;
            f16x8 v;
#pragma unroll
            for (int j = 0; j < 8; j++) v[j] = (_Float16)Tf[(cb + j) * 132 + q];
            bf[nt] = v;
        }
#pragma unroll
        for (int mt = 0; mt < 4; mt++)
#pragma unroll
            for (int nt = 0; nt < 4; nt++)
                acc[mt][nt] = __builtin_amdgcn_mfma_f32_16x16x32_f16(af[mt], bf[nt], acc[mt][nt], 0, 0, 0);
    }
#pragma unroll
    for (int mt = 0; mt < 4; mt++) {
        int o = wm * 64 + mt * 16 + (lane >> 4) * 4;
        float4 b4 = *(const float4*)(bias + o);
#pragma unroll
        for (int nt = 0; nt < 4; nt++) {
            int pix = pix0g + wn * 64 + nt * 16 + (lane & 15);
            f32x4 a = acc[mt][nt];
            h2v lo = { (_Float16)(a[0] + b4.x), (_Float16)(a[1] + b4.y) };
            h2v hi = { (_Float16)(a[2] + b4.z), (_Float16)(a[3] + b4.w) };
            uint2 v = { h2u(lo), h2u(hi) };
            *(uint2*)(X + (size_t)pix * 64 + (o >> 1)) = v;
        }
    }
}

// ---------------------------------------------------------------------------
// line_v3: 8 lines/block. 16B gather loads, bn1 folded into c1, fc2 fused
// into c3 epilogue. LDS 37.9 KB -> 4 blocks/CU.
// ---------------------------------------------------------------------------
__global__ __launch_bounds__(256, 4) void line_v3(
    const unsigned int* __restrict__ X,      // [131072][64] h2 units
    const float* __restrict__ lines,
    const unsigned int* __restrict__ c1w16, const float* __restrict__ c1b,
    const unsigned int* __restrict__ c2w16, const float* __restrict__ c2b,
    const unsigned int* __restrict__ c3w16, const float* __restrict__ c3b,
    const unsigned int* __restrict__ wfc2p, const float* __restrict__ bfc2,
    const unsigned int* __restrict__ bn_pk,
    float* __restrict__ out)
{
    __shared__ int geoB[256];
    __shared__ unsigned int geoWA[256], geoWB[256];
    __shared__ h2v xp[64 * 65];   // [c2][col] stride 65, col = line*8 + p
    __shared__ h2v hb[32 * 65];   // h1, later h2out
    __shared__ h2v ap[32 * 73];   // a2 padded (9/line), later a3 [32][64]
    __shared__ float red[128];    // [og][l][j]

    const int t = threadIdx.x;
    const int n0 = blockIdx.x * 8;
    const int col = t & 63;
    const int og = t >> 6;

    // ---- geometry: one thread per sample point ----
    {
        int l = t >> 5, k = t & 31;
        int n = n0 + l;
        float4 ln = *(const float4*)(lines + n * 4);
        float lam = (float)k / 31.0f;
        float px = ln.x * lam + ln.z * (1.f - lam) - 0.5f;
        float py = ln.y * lam + ln.w * (1.f - lam) - 0.5f;
        float px0 = fminf(fmaxf(floorf(px), 0.f), 255.f);
        float py0 = fminf(fmaxf(floorf(py), 0.f), 255.f);
        float dx = px - px0, dy = py - py0;
        float ex = 1.f - dx, ey = 1.f - dy;
        h2v wA = { (_Float16)(ex * ey), (_Float16)(dx * ey) };
        h2v wB = { (_Float16)(ex * dy), (_Float16)(dx * dy) };
        int b = (n >= LPB) ? 1 : 0;
        int pixflat = (b << 16) + ((int)px0 << 8) + (int)py0;
        geoB[t] = pixflat << 6;                  // h2-unit index
        geoWA[t] = h2u(wA); geoWB[t] = h2u(wB);
    }
    __syncthreads();

    // ---- gather + maxpool4: uint4 (8 channels) per load ----
    {
        const int c8 = t & 15;          // channel-oct 0..15 (8 ch each)
        const int sub = t >> 4;         // 0..15
        const int line = sub >> 1;
        const int gbase = (sub & 1) * 4;
        const uint4* xq = (const uint4*)X;
#pragma unroll
        for (int lg = 0; lg < 4; lg++) {
            int g = gbase + lg;
            int ptb = line * 32 + g * 4;
            h2v m0, m1, m2, m3;
#pragma unroll
            for (int s = 0; s < 4; s++) {
                int pt = ptb + s;
                int base4 = (geoB[pt] >> 2) + c8;
                h2v wA = u2h(geoWA[pt]), wB = u2h(geoWB[pt]);
                uint4 q00 = xq[base4];
                uint4 q10 = xq[base4 + 4096];
                uint4 q01 = xq[base4 + 16];
                uint4 q11 = xq[base4 + 4112];
                h2v w00 = { wA[0], wA[0] }, w10 = { wA[1], wA[1] };
                h2v w01 = { wB[0], wB[0] }, w11 = { wB[1], wB[1] };
                h2v v0 = u2h(q00.x) * w00 + u2h(q10.x) * w10 + u2h(q01.x) * w01 + u2h(q11.x) * w11;
                h2v v1 = u2h(q00.y) * w00 + u2h(q10.y) * w10 + u2h(q01.y) * w01 + u2h(q11.y) * w11;
                h2v v2 = u2h(q00.z) * w00 + u2h(q10.z) * w10 + u2h(q01.z) * w01 + u2h(q11.z) * w11;
                h2v v3 = u2h(q00.w) * w00 + u2h(q10.w) * w10 + u2h(q01.w) * w01 + u2h(q11.w) * w11;
                if (s == 0) { m0 = v0; m1 = v1; m2 = v2; m3 = v3; }
                else { m0 = hmax2v(m0, v0); m1 = hmax2v(m1, v1);
                       m2 = hmax2v(m2, v2); m3 = hmax2v(m3, v3); }
            }
            int colw = line * 8 + g;
            xp[(c8 * 4 + 0) * 65 + colw] = m0;
            xp[(c8 * 4 + 1) * 65 + colw] = m1;
            xp[(c8 * 4 + 2) * 65 + colw] = m2;
            xp[(c8 * 4 + 3) * 65 + colw] = m3;
        }
    }
    __syncthreads();

    // ---- c1 (128->64) with bn1+relu folded into the operand read ----
    {
        const int obU = __builtin_amdgcn_readfirstlane(og * 16);
        float acc[16];
#pragma unroll
        for (int i = 0; i < 16; i++) acc[i] = c1b[obU + i];
#pragma unroll 8
        for (int c2 = 0; c2 < 64; c2++) {
            h2v sc = u2h(bn_pk[c2]), sh = u2h(bn_pk[64 + c2]);
            h2v av = relu2(xp[c2 * 65 + col] * sc + sh);
            unsigned int wv[16];
#pragma unroll
            for (int q = 0; q < 4; q++)
                *(uint4*)&wv[q * 4] = *(const uint4*)(c1w16 + c2 * 64 + obU + q * 4);
#pragma unroll
            for (int i = 0; i < 16; i++) acc[i] = fdot2(av, wv[i], acc[i]);
        }
#pragma unroll
        for (int j = 0; j < 8; j++) {
            h2v v = { (_Float16)acc[2 * j], (_Float16)acc[2 * j + 1] };
            hb[(obU / 2 + j) * 65 + col] = v;
        }
    }
    __syncthreads();

    // ---- a2 = relu(bn2(h1)) into padded ap (stride 9/line) ----
    {
        int c2 = t >> 3, l = t & 7;
        h2v sc = u2h(bn_pk[128 + c2]), sh = u2h(bn_pk[160 + c2]);
        h2v z = (h2v)(_Float16)0.f;
        ap[c2 * 73 + l * 9] = z;
#pragma unroll
        for (int p = 0; p < 8; p++)
            ap[c2 * 73 + l * 9 + 1 + p] = relu2(hb[c2 * 65 + l * 8 + p] * sc + sh);
        if (l == 7) ap[c2 * 73 + 72] = z;
    }
    __syncthreads();

    // ---- c2 conv3 (64->64) ----
    {
        const int obU = __builtin_amdgcn_readfirstlane(og * 16);
        const int l = col >> 3, p = col & 7;
        const int pos0 = l * 9 + p;
        float acc[16];
#pragma unroll
        for (int i = 0; i < 16; i++) acc[i] = c2b[obU + i];
#pragma unroll 2
        for (int i2 = 0; i2 < 32; i2++) {
            h2v a0 = ap[i2 * 73 + pos0];
            h2v a1 = ap[i2 * 73 + pos0 + 1];
            h2v a2 = ap[i2 * 73 + pos0 + 2];
            unsigned int wv[48];
#pragma unroll
            for (int tap = 0; tap < 3; tap++)
#pragma unroll
                for (int q = 0; q < 4; q++)
                    *(uint4*)&wv[tap * 16 + q * 4] =
                        *(const uint4*)(c2w16 + (i2 * 3 + tap) * 64 + obU + q * 4);
#pragma unroll
            for (int i = 0; i < 16; i++) {
                acc[i] = fdot2(a0, wv[i], acc[i]);
                acc[i] = fdot2(a1, wv[16 + i], acc[i]);
                acc[i] = fdot2(a2, wv[32 + i], acc[i]);
            }
        }
#pragma unroll
        for (int j = 0; j < 8; j++) {
            h2v v = { (_Float16)acc[2 * j], (_Float16)acc[2 * j + 1] };
            hb[(obU / 2 + j) * 65 + col] = v;
        }
    }
    __syncthreads();

    // ---- a3 = relu(bn3(h2)) into ap[0..2047] (stride 64) ----
#pragma unroll
    for (int r = 0; r < 8; r++) {
        int idx = t + 256 * r;
        int c2 = idx >> 6, cl = idx & 63;
        h2v sc = u2h(bn_pk[192 + c2]), sh = u2h(bn_pk[224 + c2]);
        ap[c2 * 64 + cl] = relu2(hb[c2 * 65 + cl] * sc + sh);
    }
    __syncthreads();

    // ---- c3 (64->128) + residual + fc2 partial, fused ----
    {
        const int obU = __builtin_amdgcn_readfirstlane(og * 32);
        float acc[32];
#pragma unroll
        for (int i = 0; i < 32; i++) acc[i] = c3b[obU + i];
#pragma unroll 2
        for (int i2 = 0; i2 < 32; i2++) {
            h2v av = ap[i2 * 64 + col];
            unsigned int wv[32];
#pragma unroll
            for (int q = 0; q < 8; q++)
                *(uint4*)&wv[q * 4] = *(const uint4*)(c3w16 + i2 * 128 + obU + q * 4);
#pragma unroll
            for (int i = 0; i < 32; i++) acc[i] = fdot2(av, wv[i], acc[i]);
        }
        const int p = col & 7, l = col >> 3;
        h2v yv[16];
#pragma unroll
        for (int j = 0; j < 16; j++) {
            h2v hv = { (_Float16)acc[2 * j], (_Float16)acc[2 * j + 1] };
            yv[j] = relu2(xp[(obU / 2 + j) * 65 + col] + hv);
        }
        float aj[4] = { 0.f, 0.f, 0.f, 0.f };
#pragma unroll
        for (int j = 0; j < 4; j++) {
            unsigned int wv2[16];
#pragma unroll
            for (int q = 0; q < 4; q++)
                *(uint4*)&wv2[q * 4] = *(const uint4*)(wfc2p + (j * 8 + p) * 64 + obU / 2 + q * 4);
#pragma unroll
            for (int j16 = 0; j16 < 16; j16++) aj[j] = fdot2(yv[j16], wv2[j16], aj[j]);
        }
#pragma unroll
        for (int off = 4; off > 0; off >>= 1) {
#pragma unroll
            for (int j = 0; j < 4; j++) aj[j] += __shfl_down(aj[j], off, 8);
        }
        if ((t & 7) == 0) {
#pragma unroll
            for (int j = 0; j < 4; j++) red[og * 32 + l * 4 + j] = aj[j];
        }
    }
    __syncthreads();

    // ---- final reduce + softmax ----
    if (t < 8) {
        float lg[4];
#pragma unroll
        for (int j = 0; j < 4; j++)
            lg[j] = bfc2[j] + red[t * 4 + j] + red[32 + t * 4 + j]
                  + red[64 + t * 4 + j] + red[96 + t * 4 + j];
        float mx = fmaxf(fmaxf(lg[0], lg[1]), fmaxf(lg[2], lg[3]));
        float e0 = expf(lg[0] - mx), e1 = expf(lg[1] - mx);
        float e2 = expf(lg[2] - mx), e3 = expf(lg[3] - mx);
        float s = 1.f / (e0 + e1 + e2 + e3);
        float4 r = { e0 * s, e1 * s, e2 * s, e3 * s };
        *(float4*)(out + (size_t)(n0 + t) * 4) = r;
    }
}

extern "C" void kernel_launch(void* const* d_in, const int* in_sizes, int n_in,
                              void* d_out, int out_size, void* d_ws, size_t ws_size,
                              hipStream_t stream) {
    const float* feature = (const float*)d_in[0];
    const float* lines   = (const float*)d_in[1];
    const float* w_fc1   = (const float*)d_in[2];
    const float* b_fc1   = (const float*)d_in[3];
    const float* bn1     = (const float*)d_in[4];
    const float* c1_w    = (const float*)d_in[5];
    const float* c1_b    = (const float*)d_in[6];
    const float* bn2     = (const float*)d_in[7];
    const float* c2_w    = (const float*)d_in[8];
    const float* c2_b    = (const float*)d_in[9];
    const float* bn3     = (const float*)d_in[10];
    const float* c3_w    = (const float*)d_in[11];
    const float* c3_b    = (const float*)d_in[12];
    const float* w_fc2   = (const float*)d_in[13];
    const float* b_fc2   = (const float*)d_in[14];
    float* out = (float*)d_out;

    char* ws = (char*)d_ws;
    unsigned int* X     = (unsigned int*)ws;                 // 33,554,432 B
    _Float16*     wf16  = (_Float16*)(ws + 33554432);        // 65,536 B
    unsigned int* c1w16 = (unsigned int*)(ws + 33619968);    // 16,384 B
    unsigned int* c2w16 = (unsigned int*)(ws + 33636352);    // 24,576 B
    unsigned int* c3w16 = (unsigned int*)(ws + 33660928);    // 16,384 B
    unsigned int* wfc2p = (unsigned int*)(ws + 33677312);    // 8,192 B
    unsigned int* bn_pk = (unsigned int*)(ws + 33685504);    // 1,024 B

    prep_small<<<193, 256, 0, stream>>>(w_fc1, c1_w, c2_w, c3_w, w_fc2, bn1, bn2, bn3,
                                        wf16, c1w16, c2w16, c3w16, wfc2p, bn_pk);
    fc1_fused<<<1024, 256, 0, stream>>>(feature, wf16, b_fc1, X);
    line_v3<<<1250, 256, 0, stream>>>(X, lines, c1w16, c1_b, c2w16, c2_b,
                                      c3w16, c3_b, wfc2p, b_fc2, bn_pk, out);
}